// Round 2
// baseline (625.532 us; speedup 1.0000x reference)
//
#include <hip/hip_runtime.h>

#define BATCH 32768
#define TT 11
#define EE 128
#define HH 20

// ws layout (bytes):
//   [0 .. 8192)                    : double slots[1024]
//        step t stats: slots[t*64 + j] = sum_j, slots[t*64 + 20 + j] = sumsq_j (j<20)
//        loss sum: slots[704], acc sum: slots[705]
//   [8192 .. +28835840)            : float zc  [T][H][B]   (28.8 MB)
//   [+28835840 .. +57671680)       : float hist[T][H][B]   (28.8 MB)  pre-norm hn history
//   [+57671680 .. +60293120)       : float hs  [H][B]      (2.6 MB)   pre-norm hs of current step
#define ZC_OFF   8192
#define HIST_OFF (8192 + 28835840)
#define HS_OFF   (8192 + 2*28835840)

__device__ __forceinline__ float waveRed(float v) {
    #pragma unroll
    for (int m = 32; m > 0; m >>= 1) v += __shfl_xor(v, m, 64);
    return v;
}

// ---------------- Kernel A: per-(b,t) input MLP -> zc[t][j][b]; block 0 zeroes slots ----------------
__global__ __launch_bounds__(128) void mlp_kernel(
    const float* __restrict__ bx, const float* __restrict__ w1, const float* __restrict__ b1,
    const float* __restrict__ w2, const float* __restrict__ b2,
    const float* __restrict__ c,
    float* __restrict__ zc, double* __restrict__ slots)
{
    __shared__ float act[100 * 128];   // staging so runtime-index reads stay in LDS, not scratch
    const int tid = threadIdx.x;
    if (blockIdx.x == 0) {
        for (int i = tid; i < 1024; i += 128) slots[i] = 0.0;  // later kernels are stream-ordered after us
    }
    const int gid = blockIdx.x * 128 + tid;
    const int t = gid >> 15;            // gid / 32768
    const int b = gid & (BATCH - 1);
    const float* xp = bx + ((size_t)b * TT + t) * EE;

    // phase 1: s1[50] = relu(x @ w1 + b1)
    float s1r[50];
    #pragma unroll
    for (int k = 0; k < 50; ++k) s1r[k] = b1[k];
    for (int e4 = 0; e4 < 32; ++e4) {
        const float4 xv = *(const float4*)(xp + e4 * 4);
        const float* wr = w1 + e4 * 4 * 50;
        #pragma unroll
        for (int k = 0; k < 50; ++k) s1r[k] = fmaf(xv.x, wr[k], s1r[k]);
        #pragma unroll
        for (int k = 0; k < 50; ++k) s1r[k] = fmaf(xv.y, wr[50 + k], s1r[k]);
        #pragma unroll
        for (int k = 0; k < 50; ++k) s1r[k] = fmaf(xv.z, wr[100 + k], s1r[k]);
        #pragma unroll
        for (int k = 0; k < 50; ++k) s1r[k] = fmaf(xv.w, wr[150 + k], s1r[k]);
    }
    #pragma unroll
    for (int k = 0; k < 50; ++k) act[k * 128 + tid] = fmaxf(s1r[k], 0.f);

    // phase 2: z[100] = relu(s1 @ w2 + b2)
    float zr[100];
    #pragma unroll
    for (int k = 0; k < 100; ++k) zr[k] = b2[k];
    for (int f = 0; f < 50; ++f) {
        const float sv = act[f * 128 + tid];
        const float* wr = w2 + f * 100;
        #pragma unroll
        for (int k = 0; k < 100; ++k) zr[k] = fmaf(sv, wr[k], zr[k]);
    }
    #pragma unroll
    for (int k = 0; k < 100; ++k) act[k * 128 + tid] = fmaxf(zr[k], 0.f);

    // phase 3: zc[20] = z @ c
    float zcr[HH];
    #pragma unroll
    for (int j = 0; j < HH; ++j) zcr[j] = 0.f;
    for (int q = 0; q < 100; ++q) {
        const float zv = act[q * 128 + tid];
        const float* cr = c + q * HH;
        #pragma unroll
        for (int j = 0; j < HH; ++j) zcr[j] = fmaf(zv, cr[j], zcr[j]);
    }
    #pragma unroll
    for (int j = 0; j < HH; ++j) zc[((size_t)(t * HH + j) << 15) + b] = zcr[j];
}

// ---------------- Kernel B (x11): one scan step ----------------
// Normalizes hs[t-1] via slots stats (written by previous step kernel; stream-ordered),
// computes hn_t, fast-weight attractor term from hist, writes hs_t + stats atomics.
__global__ __launch_bounds__(128) void step_kernel(
    const float* __restrict__ zc, const float* __restrict__ lp, const float* __restrict__ ep,
    const float* __restrict__ w, const float* __restrict__ g, const float* __restrict__ bb,
    float* __restrict__ hist, float* __restrict__ hs_buf, double* __restrict__ slots, int t)
{
    __shared__ float red[2][40];
    const int tid = threadIdx.x;
    const int b = blockIdx.x * 128 + tid;     // 256 blocks * 128 = BATCH
    const int lane = tid & 63, wv = tid >> 6;
    const float l0 = lp[0], e0 = ep[0];

    // carry h = BN(hs_{t-1}) (or 0 at t=0)
    float h[HH];
    if (t == 0) {
        #pragma unroll
        for (int j = 0; j < HH; ++j) h[j] = 0.f;
    } else {
        #pragma unroll
        for (int j = 0; j < HH; ++j) {
            const double s1 = slots[(t - 1) * 64 + j];
            const double s2 = slots[(t - 1) * 64 + HH + j];
            const double mu = s1 * (1.0 / 32768.0);
            const double var = s2 * (1.0 / 32768.0) - mu * mu;
            const float muf = (float)mu;
            const float rsig = 1.0f / sqrtf((float)var);
            const float hv = hs_buf[(j << 15) + b];
            h[j] = fmaxf(fmaf(g[j] * rsig, hv - muf, bb[j]), 0.f);
        }
    }

    float zct[HH];
    #pragma unroll
    for (int j = 0; j < HH; ++j) zct[j] = zc[((t * HH + j) << 15) + b];

    // hn = relu(h @ w + zc_t)
    float hn[HH];
    #pragma unroll
    for (int j = 0; j < HH; ++j) {
        float a = zct[j];
        #pragma unroll
        for (int i = 0; i < HH; ++i) a = fmaf(h[i], w[i * HH + j], a);
        hn[j] = fmaxf(a, 0.f);
    }
    #pragma unroll
    for (int j = 0; j < HH; ++j) hist[((t * HH + j) << 15) + b] = hn[j];

    // pv = hn @ a_t = e * sum_{s<=t} l^(t-s) (hn . hn_s) hn_s
    float pv[HH];
    {
        float d = 0.f;
        #pragma unroll
        for (int j = 0; j < HH; ++j) d = fmaf(hn[j], hn[j], d);
        const float cd = e0 * d;
        #pragma unroll
        for (int j = 0; j < HH; ++j) pv[j] = cd * hn[j];
    }
    float coef = e0 * l0;
    for (int s = t - 1; s >= 0; --s) {
        float tv[HH];
        #pragma unroll
        for (int j = 0; j < HH; ++j) tv[j] = hist[((s * HH + j) << 15) + b];
        float d = 0.f;
        #pragma unroll
        for (int j = 0; j < HH; ++j) d = fmaf(hn[j], tv[j], d);
        const float cd = coef * d;
        #pragma unroll
        for (int j = 0; j < HH; ++j) pv[j] = fmaf(cd, tv[j], pv[j]);
        coef *= l0;
    }

    // hs = hn @ w + zc_t + pv  (pre-norm; stored for next kernel)
    float hs[HH];
    #pragma unroll
    for (int j = 0; j < HH; ++j) {
        float a = zct[j] + pv[j];
        #pragma unroll
        for (int i = 0; i < HH; ++i) a = fmaf(hn[i], w[i * HH + j], a);
        hs[j] = a;
        hs_buf[(j << 15) + b] = a;
    }

    // per-channel sum / sumsq -> fp64 atomics
    #pragma unroll
    for (int j = 0; j < HH; ++j) {
        const float sm = waveRed(hs[j]);
        const float sq = waveRed(hs[j] * hs[j]);
        if (lane == 0) { red[wv][j] = sm; red[wv][HH + j] = sq; }
    }
    __syncthreads();
    if (tid < 2 * HH) {
        atomicAdd(&slots[t * 64 + tid], (double)(red[0][tid] + red[1][tid]));
    }
}

// ---------------- Kernel C: BN of step 10 + head MLP + loss/acc atomics ----------------
__global__ __launch_bounds__(128) void head_kernel(
    const float* __restrict__ hs_buf, const float* __restrict__ by,
    const float* __restrict__ g, const float* __restrict__ bb,
    const float* __restrict__ w3, const float* __restrict__ b3,
    const float* __restrict__ w4, const float* __restrict__ b4,
    double* __restrict__ slots)
{
    __shared__ float stg[100 * 128];
    __shared__ float red[2][2];
    const int tid = threadIdx.x;
    const int b = blockIdx.x * 128 + tid;
    const int lane = tid & 63, wv = tid >> 6;

    float h[HH];
    #pragma unroll
    for (int j = 0; j < HH; ++j) {
        const double s1 = slots[10 * 64 + j];
        const double s2 = slots[10 * 64 + HH + j];
        const double mu = s1 * (1.0 / 32768.0);
        const double var = s2 * (1.0 / 32768.0) - mu * mu;
        const float muf = (float)mu;
        const float rsig = 1.0f / sqrtf((float)var);
        const float hv = hs_buf[(j << 15) + b];
        h[j] = fmaxf(fmaf(g[j] * rsig, hv - muf, bb[j]), 0.f);
    }

    // hf = relu(h @ w3 + b3)   (all-static indices -> registers)
    float hf[100];
    #pragma unroll
    for (int k = 0; k < 100; ++k) hf[k] = b3[k];
    #pragma unroll
    for (int i = 0; i < HH; ++i) {
        const float hv = h[i];
        const float* wr = w3 + i * 100;
        #pragma unroll
        for (int k = 0; k < 100; ++k) hf[k] = fmaf(hv, wr[k], hf[k]);
    }
    #pragma unroll
    for (int k = 0; k < 100; ++k) stg[k * 128 + tid] = fmaxf(hf[k], 0.f);

    // logits = hf @ w4 + b4
    float lg[EE];
    #pragma unroll
    for (int e = 0; e < EE; ++e) lg[e] = b4[e];
    for (int k = 0; k < 100; ++k) {
        const float hv = stg[k * 128 + tid];
        const float* wr = w4 + k * EE;
        #pragma unroll
        for (int e = 0; e < EE; ++e) lg[e] = fmaf(hv, wr[e], lg[e]);
    }

    // log-softmax + loss + acc
    float mx = lg[0]; int am = 0;
    #pragma unroll
    for (int e = 1; e < EE; ++e) { if (lg[e] > mx) { mx = lg[e]; am = e; } }
    float se = 0.f;
    #pragma unroll
    for (int e = 0; e < EE; ++e) se += expf(lg[e] - mx);
    const float lse = logf(se);

    const float* byp = by + (size_t)b * EE;
    float loss = 0.f, bymax = -3.402823e38f; int byam = 0;
    #pragma unroll
    for (int e4 = 0; e4 < 32; ++e4) {
        const float4 v = *(const float4*)(byp + e4 * 4);
        const int e = e4 * 4;
        if (v.x > bymax) { bymax = v.x; byam = e; }
        if (v.y > bymax) { bymax = v.y; byam = e + 1; }
        if (v.z > bymax) { bymax = v.z; byam = e + 2; }
        if (v.w > bymax) { bymax = v.w; byam = e + 3; }
        loss = fmaf(-v.x, lg[e] - mx - lse, loss);
        loss = fmaf(-v.y, lg[e + 1] - mx - lse, loss);
        loss = fmaf(-v.z, lg[e + 2] - mx - lse, loss);
        loss = fmaf(-v.w, lg[e + 3] - mx - lse, loss);
    }
    const float acc_i = (am == byam) ? 1.f : 0.f;

    const float ls = waveRed(loss);
    const float as = waveRed(acc_i);
    if (lane == 0) { red[wv][0] = ls; red[wv][1] = as; }
    __syncthreads();
    if (tid == 0) atomicAdd(&slots[704], (double)(red[0][0] + red[1][0]));
    if (tid == 1) atomicAdd(&slots[705], (double)(red[0][1] + red[1][1]));
}

// ---------------- Kernel D: finalize ----------------
__global__ void finalize_kernel(const double* __restrict__ slots, float* __restrict__ out) {
    out[0] = (float)(slots[704] * (1.0 / 32768.0));
    out[1] = (float)(slots[705] * (1.0 / 32768.0));
}

extern "C" void kernel_launch(void* const* d_in, const int* in_sizes, int n_in,
                              void* d_out, int out_size, void* d_ws, size_t ws_size,
                              hipStream_t stream) {
    const float* bx = (const float*)d_in[0];
    const float* by = (const float*)d_in[1];
    const float* l  = (const float*)d_in[2];
    const float* e  = (const float*)d_in[3];
    const float* w1 = (const float*)d_in[4];
    const float* b1 = (const float*)d_in[5];
    const float* w2 = (const float*)d_in[6];
    const float* b2 = (const float*)d_in[7];
    const float* w3 = (const float*)d_in[8];
    const float* b3 = (const float*)d_in[9];
    const float* w4 = (const float*)d_in[10];
    const float* b4 = (const float*)d_in[11];
    const float* w  = (const float*)d_in[12];
    const float* c  = (const float*)d_in[13];
    const float* g  = (const float*)d_in[14];
    const float* bb = (const float*)d_in[15];

    double* slots = (double*)d_ws;
    float*  zc    = (float*)((char*)d_ws + ZC_OFF);
    float*  hist  = (float*)((char*)d_ws + HIST_OFF);
    float*  hs    = (float*)((char*)d_ws + HS_OFF);
    float*  out   = (float*)d_out;

    hipLaunchKernelGGL(mlp_kernel, dim3(2816), dim3(128), 0, stream,
                       bx, w1, b1, w2, b2, c, zc, slots);
    for (int t = 0; t < TT; ++t) {
        hipLaunchKernelGGL(step_kernel, dim3(256), dim3(128), 0, stream,
                           zc, l, e, w, g, bb, hist, hs, slots, t);
    }
    hipLaunchKernelGGL(head_kernel, dim3(256), dim3(128), 0, stream,
                       hs, by, g, bb, w3, b3, w4, b4, slots);
    hipLaunchKernelGGL(finalize_kernel, dim3(1), dim3(1), 0, stream, slots, out);
}